// Round 8
// baseline (657.732 us; speedup 1.0000x reference)
//
#include <hip/hip_runtime.h>
#include <hip/hip_bf16.h>
#include <math.h>

// ---------------------------------------------------------------------------
// GAT 3-layer forward.
// R8: GEMM staging rebuilt on __builtin_amdgcn_global_load_lds (16B, async,
//     no VGPR round-trip). Unpadded [row][32k] LDS tiles; global-source XOR
//     swizzle (kc ^ ((row>>1)&3)) makes lane-slot data match a conflict-free
//     ds_read_b128 pattern. 48/32 KB LDS -> 3/5 blocks per CU.
//     Aggregation (single-pass) and prep unchanged from R7.
// ---------------------------------------------------------------------------

#define NEG_SLOPE 0.2f
#define EPS_SM 1e-16f

typedef __bf16 bf16x8 __attribute__((ext_vector_type(8)));
typedef float f32x4 __attribute__((ext_vector_type(4)));

__device__ __forceinline__ void async_copy16(unsigned short* ldsdst,
                                             const unsigned short* g) {
    __builtin_amdgcn_global_load_lds(
        (const __attribute__((address_space(1))) unsigned int*)g,
        (__attribute__((address_space(3))) unsigned int*)ldsdst, 16, 0, 0);
}

__device__ __forceinline__ float wave_allred_sum(float v) {
#pragma unroll
    for (int o = 32; o > 0; o >>= 1) v += __shfl_xor(v, o, 64);
    return v;
}
__device__ __forceinline__ float4 lrelu4(float4 v) {
    v.x = (v.x < 0.f) ? NEG_SLOPE * v.x : v.x;
    v.y = (v.y < 0.f) ? NEG_SLOPE * v.y : v.y;
    v.z = (v.z < 0.f) ? NEG_SLOPE * v.z : v.z;
    v.w = (v.w < 0.f) ? NEG_SLOPE * v.w : v.w;
    return v;
}

// ---------------- CSR build ----------------
__global__ void hist_kernel(const int* __restrict__ ei, int E, int N,
                            int* __restrict__ cnt) {
    int e = blockIdx.x * 256 + threadIdx.x;
    int ET = E + N;
    if (e >= ET) return;
    int dst = (e < E) ? ei[E + e] : (e - E);
    atomicAdd(&cnt[dst], 1);
}

__global__ void scan_block(const int* __restrict__ cnt, int n_cnt,
                           int* __restrict__ offs, int n_off,
                           int* __restrict__ bsums) {
    __shared__ int buf[1024];
    int gid = blockIdx.x * 1024 + threadIdx.x;
    int v = (gid < n_cnt) ? cnt[gid] : 0;
    buf[threadIdx.x] = v;
    __syncthreads();
#pragma unroll
    for (int off = 1; off < 1024; off <<= 1) {
        int t = (threadIdx.x >= off) ? buf[threadIdx.x - off] : 0;
        __syncthreads();
        buf[threadIdx.x] += t;
        __syncthreads();
    }
    if (gid < n_off) offs[gid] = buf[threadIdx.x] - v;
    if (threadIdx.x == 1023) bsums[blockIdx.x] = buf[1023];
}

__global__ void scan_sums(int* __restrict__ bsums, int nb) {
    int l = threadIdx.x;
    int v = (l < nb) ? bsums[l] : 0;
    int inc = v;
#pragma unroll
    for (int o = 1; o < 64; o <<= 1) {
        int t = __shfl_up(inc, o, 64);
        if (l >= o) inc += t;
    }
    if (l < nb) bsums[l] = inc - v;  // exclusive
}

__global__ void scan_add(int* __restrict__ offs, int n_off,
                         const int* __restrict__ bsums) {
    int gid = blockIdx.x * 1024 + threadIdx.x;
    if (gid < n_off) offs[gid] += bsums[blockIdx.x];
}

__global__ void fill_csr(const int* __restrict__ ei, int E, int N,
                         const int* __restrict__ offs, int* __restrict__ fil,
                         int* __restrict__ csr) {
    int e = blockIdx.x * 256 + threadIdx.x;
    int ET = E + N;
    if (e >= ET) return;
    int src, dst;
    if (e < E) { src = ei[e]; dst = ei[E + e]; }
    else       { src = dst = e - E; }
    int pos = offs[dst] + atomicAdd(&fil[dst], 1);
    csr[pos] = src;
}

// ---------------- W transpose + hi/lo bf16 split ----------------
__global__ void wsplit_t(const float* __restrict__ W, int K, int N,
                         unsigned short* __restrict__ hi,
                         unsigned short* __restrict__ lo) {
    int idx = blockIdx.x * 256 + threadIdx.x;  // over N*K, k-fast
    if (idx >= N * K) return;
    int n = idx / K, k = idx - n * K;
    float v = W[(size_t)k * N + n];
    unsigned u = __float_as_uint(v);
    float d = v - __uint_as_float(u & 0xffff0000u);
    hi[idx] = (unsigned short)(u >> 16);
    lo[idx] = (unsigned short)(__float_as_uint(d) >> 16);
}

// ---------------- X hi/lo split ----------------
__global__ void split_x(const float* __restrict__ X,
                        unsigned short* __restrict__ hi,
                        unsigned short* __restrict__ lo, int total8) {
    int idx = blockIdx.x * 256 + threadIdx.x;
    if (idx >= total8) return;
    const float4* xp = (const float4*)X + (size_t)idx * 2;
    float4 v0 = xp[0], v1 = xp[1];
    float vf[8] = {v0.x, v0.y, v0.z, v0.w, v1.x, v1.y, v1.z, v1.w};
    unsigned h[4], l[4];
#pragma unroll
    for (int i = 0; i < 4; ++i) {
        unsigned u0 = __float_as_uint(vf[2 * i]);
        unsigned u1 = __float_as_uint(vf[2 * i + 1]);
        h[i] = (u0 >> 16) | (u1 & 0xffff0000u);
        float d0 = vf[2 * i]     - __uint_as_float(u0 & 0xffff0000u);
        float d1 = vf[2 * i + 1] - __uint_as_float(u1 & 0xffff0000u);
        l[i] = (__float_as_uint(d0) >> 16) | (__float_as_uint(d1) & 0xffff0000u);
    }
    ((uint4*)hi)[idx] = make_uint4(h[0], h[1], h[2], h[3]);
    ((uint4*)lo)[idx] = make_uint4(l[0], l[1], l[2], l[3]);
}

// ---------------- layers 1-2 GEMM: BM=128 BN=256 BK=32, 512 thr ------------
// async global->LDS staging, XOR-swizzled chunks, fused al epilogue.
// LDS (ushorts): Ah[0,4096) Al[4096,8192) Bh[8192,16384) Bl[16384,24576)
__global__ __launch_bounds__(512) void gemm_mfma_wide(
    const unsigned short* __restrict__ A_hi,
    const unsigned short* __restrict__ A_lo,
    const unsigned short* __restrict__ Bt_hi,
    const unsigned short* __restrict__ Bt_lo, float* __restrict__ C,
    const float* __restrict__ a_s, const float* __restrict__ a_d,
    float* __restrict__ als, float* __restrict__ ald, int M) {
    const int K = 256, N = 256;
    __shared__ unsigned short lds[24576];  // 48 KB
    const int bm = blockIdx.x * 128;
    const int tid = threadIdx.x;
    const int w = tid >> 6, lane = tid & 63;
    const int wm = (w >> 2) * 64, wn = (w & 3) * 64;
    const int l16 = lane & 15, q = lane >> 4;
    const int sw = (l16 >> 1) & 3;
    const int kqp = (q ^ sw) * 8;            // swizzled k-chunk for frag reads
    const int rl = lane >> 2, kc = lane & 3; // staging lane decomposition

    f32x4 acc[4][4];
#pragma unroll
    for (int i = 0; i < 4; ++i)
#pragma unroll
        for (int j = 0; j < 4; ++j) acc[i][j] = (f32x4){0.f, 0.f, 0.f, 0.f};

    for (int k0 = 0; k0 < K; k0 += 32) {
        // ---- async staging: 48 x 1KB chunks, wave w does chunks 6w..6w+5 --
#pragma unroll
        for (int j = 0; j < 6; ++j) {
            const int c = w * 6 + j;
            const unsigned short* src;
            int row0, ldsbase, isA;
            if (c < 8)       { src = A_hi;  row0 = c * 16;        ldsbase = c * 512;            isA = 1; }
            else if (c < 16) { src = A_lo;  row0 = (c - 8) * 16;  ldsbase = 4096 + (c-8)*512;   isA = 1; }
            else if (c < 32) { src = Bt_hi; row0 = (c - 16) * 16; ldsbase = 8192 + (c-16)*512;  isA = 0; }
            else             { src = Bt_lo; row0 = (c - 32) * 16; ldsbase = 16384 + (c-32)*512; isA = 0; }
            const int r = row0 + rl;
            const int gcol = k0 + ((kc ^ ((r >> 1) & 3)) * 8);
            if (isA) {
                if (bm + r < M)
                    async_copy16(&lds[ldsbase], A_hi == src
                        ? (A_hi + (size_t)(bm + r) * K + gcol)
                        : (A_lo + (size_t)(bm + r) * K + gcol));
            } else {
                async_copy16(&lds[ldsbase], src + (size_t)r * K + gcol);
            }
        }
        __syncthreads();
        bf16x8 aH[4], aL[4], bH[4], bL[4];
#pragma unroll
        for (int t = 0; t < 4; ++t) {
            aH[t] = *(const bf16x8*)&lds[(wm + t * 16 + l16) * 32 + kqp];
            aL[t] = *(const bf16x8*)&lds[4096 + (wm + t * 16 + l16) * 32 + kqp];
            bH[t] = *(const bf16x8*)&lds[8192 + (wn + t * 16 + l16) * 32 + kqp];
            bL[t] = *(const bf16x8*)&lds[16384 + (wn + t * 16 + l16) * 32 + kqp];
        }
#pragma unroll
        for (int i = 0; i < 4; ++i)
#pragma unroll
            for (int j = 0; j < 4; ++j) {
                acc[i][j] = __builtin_amdgcn_mfma_f32_16x16x32_bf16(
                    aH[i], bH[j], acc[i][j], 0, 0, 0);
                acc[i][j] = __builtin_amdgcn_mfma_f32_16x16x32_bf16(
                    aH[i], bL[j], acc[i][j], 0, 0, 0);
                acc[i][j] = __builtin_amdgcn_mfma_f32_16x16x32_bf16(
                    aL[i], bH[j], acc[i][j], 0, 0, 0);
            }
        __syncthreads();
    }

    // epilogue 1: C store (C/D layout: col = l16, row = q*4 + reg)
#pragma unroll
    for (int i = 0; i < 4; ++i) {
#pragma unroll
        for (int r = 0; r < 4; ++r) {
            int row = bm + wm + i * 16 + q * 4 + r;
            if (row < M) {
                float* cp = C + (size_t)row * N + wn + l16;
                cp[0]  = acc[i][0][r];
                cp[16] = acc[i][1][r];
                cp[32] = acc[i][2][r];
                cp[48] = acc[i][3][r];
            }
        }
    }

    // epilogue 2: fused al_s / al_d (wave w owns head wn>>6)
    const int head = wn >> 6;
    float asc[4], adc[4];
#pragma unroll
    for (int j = 0; j < 4; ++j) {
        asc[j] = a_s[head * 64 + 16 * j + l16];
        adc[j] = a_d[head * 64 + 16 * j + l16];
    }
#pragma unroll
    for (int i = 0; i < 4; ++i) {
#pragma unroll
        for (int r = 0; r < 4; ++r) {
            float ps = acc[i][0][r] * asc[0] + acc[i][1][r] * asc[1] +
                       acc[i][2][r] * asc[2] + acc[i][3][r] * asc[3];
            float pd = acc[i][0][r] * adc[0] + acc[i][1][r] * adc[1] +
                       acc[i][2][r] * adc[2] + acc[i][3][r] * adc[3];
#pragma unroll
            for (int o = 1; o < 16; o <<= 1) {
                ps += __shfl_xor(ps, o, 64);
                pd += __shfl_xor(pd, o, 64);
            }
            int row = bm + wm + i * 16 + q * 4 + r;
            if (l16 == i * 4 + r && row < M) {
                als[row * 4 + head] = ps;
                ald[row * 4 + head] = pd;
            }
        }
    }
}

// ---------------- layer-3 GEMM: BM=128 BN=128 BK=32, 256 thr ---------------
// LDS (ushorts): Ah[0,4096) Al[4096,8192) Bh[8192,12288) Bl[12288,16384)
__global__ __launch_bounds__(256) void gemm_mfma_n128(
    const unsigned short* __restrict__ A_hi,
    const unsigned short* __restrict__ A_lo,
    const unsigned short* __restrict__ Bt_hi,
    const unsigned short* __restrict__ Bt_lo, float* __restrict__ C,
    const float* __restrict__ a_s, const float* __restrict__ a_d,
    float* __restrict__ als, float* __restrict__ ald, int M) {
    const int K = 256, N = 128;
    __shared__ unsigned short lds[16384];  // 32 KB
    const int bm = blockIdx.x * 128;
    const int tid = threadIdx.x;
    const int w = tid >> 6, lane = tid & 63;
    const int wm = (w >> 1) * 64, wn = (w & 1) * 64;
    const int l16 = lane & 15, q = lane >> 4;
    const int sw = (l16 >> 1) & 3;
    const int kqp = (q ^ sw) * 8;
    const int rl = lane >> 2, kc = lane & 3;

    f32x4 acc[4][4];
#pragma unroll
    for (int i = 0; i < 4; ++i)
#pragma unroll
        for (int j = 0; j < 4; ++j) acc[i][j] = (f32x4){0.f, 0.f, 0.f, 0.f};

    for (int k0 = 0; k0 < K; k0 += 32) {
        // 32 x 1KB chunks, wave w does chunks 8w..8w+7
#pragma unroll
        for (int j = 0; j < 8; ++j) {
            const int c = w * 8 + j;
            const unsigned short* src;
            int row0, ldsbase, isA;
            if (c < 8)       { src = A_hi;  row0 = c * 16;        ldsbase = c * 512;            isA = 1; }
            else if (c < 16) { src = A_lo;  row0 = (c - 8) * 16;  ldsbase = 4096 + (c-8)*512;   isA = 1; }
            else if (c < 24) { src = Bt_hi; row0 = (c - 16) * 16; ldsbase = 8192 + (c-16)*512;  isA = 0; }
            else             { src = Bt_lo; row0 = (c - 24) * 16; ldsbase = 12288 + (c-24)*512; isA = 0; }
            const int r = row0 + rl;
            const int gcol = k0 + ((kc ^ ((r >> 1) & 3)) * 8);
            if (isA) {
                if (bm + r < M)
                    async_copy16(&lds[ldsbase], src + (size_t)(bm + r) * K + gcol);
            } else {
                async_copy16(&lds[ldsbase], src + (size_t)r * K + gcol);
            }
        }
        __syncthreads();
        bf16x8 aH[4], aL[4], bH[4], bL[4];
#pragma unroll
        for (int t = 0; t < 4; ++t) {
            aH[t] = *(const bf16x8*)&lds[(wm + t * 16 + l16) * 32 + kqp];
            aL[t] = *(const bf16x8*)&lds[4096 + (wm + t * 16 + l16) * 32 + kqp];
            bH[t] = *(const bf16x8*)&lds[8192 + (wn + t * 16 + l16) * 32 + kqp];
            bL[t] = *(const bf16x8*)&lds[12288 + (wn + t * 16 + l16) * 32 + kqp];
        }
#pragma unroll
        for (int i = 0; i < 4; ++i)
#pragma unroll
            for (int j = 0; j < 4; ++j) {
                acc[i][j] = __builtin_amdgcn_mfma_f32_16x16x32_bf16(
                    aH[i], bH[j], acc[i][j], 0, 0, 0);
                acc[i][j] = __builtin_amdgcn_mfma_f32_16x16x32_bf16(
                    aH[i], bL[j], acc[i][j], 0, 0, 0);
                acc[i][j] = __builtin_amdgcn_mfma_f32_16x16x32_bf16(
                    aL[i], bH[j], acc[i][j], 0, 0, 0);
            }
        __syncthreads();
    }

#pragma unroll
    for (int i = 0; i < 4; ++i) {
#pragma unroll
        for (int r = 0; r < 4; ++r) {
            int row = bm + wm + i * 16 + q * 4 + r;
            if (row < M) {
                float* cp = C + (size_t)row * N + wn + l16;
                cp[0]  = acc[i][0][r];
                cp[16] = acc[i][1][r];
                cp[32] = acc[i][2][r];
                cp[48] = acc[i][3][r];
            }
        }
    }

    float asc[4], adc[4];
#pragma unroll
    for (int j = 0; j < 4; ++j) {
        asc[j] = a_s[wn + 16 * j + l16];
        adc[j] = a_d[wn + 16 * j + l16];
    }
#pragma unroll
    for (int i = 0; i < 4; ++i) {
#pragma unroll
        for (int r = 0; r < 4; ++r) {
            float ps = acc[i][0][r] * asc[0] + acc[i][1][r] * asc[1] +
                       acc[i][2][r] * asc[2] + acc[i][3][r] * asc[3];
            float pd = acc[i][0][r] * adc[0] + acc[i][1][r] * adc[1] +
                       acc[i][2][r] * adc[2] + acc[i][3][r] * adc[3];
#pragma unroll
            for (int o = 1; o < 16; o <<= 1) {
                ps += __shfl_xor(ps, o, 64);
                pd += __shfl_xor(pd, o, 64);
            }
            int row = bm + wm + i * 16 + q * 4 + r;
            if (l16 == i * 4 + r && row < M) {
                atomicAdd(&als[row], ps);
                atomicAdd(&ald[row], pd);
            }
        }
    }
}

// ---------------- single-pass aggregation H=4 C=64 ----------------
__global__ __launch_bounds__(256) void aggregate_h4_sp(
    const float* __restrict__ h, const float4* __restrict__ als4,
    const float4* __restrict__ ald4, const int* __restrict__ offs,
    const int* __restrict__ csr, const float* __restrict__ bias,
    unsigned short* __restrict__ yh, unsigned short* __restrict__ yl, int Nn) {
    const int tid = threadIdx.x;
    const int w = tid >> 6;
    const int l = tid & 63;
    const int n = blockIdx.x * 4 + w;
    __shared__ float s_alpha[4][64][4];
    __shared__ int s_src[4][64];
    if (n >= Nn) return;

    const int base = offs[n];
    const int deg = offs[n + 1] - base;
    const float4 adv = ald4[n];
    const int head = l >> 4;

    float4 acc = make_float4(0.f, 0.f, 0.f, 0.f);
    float4 esum = make_float4(0.f, 0.f, 0.f, 0.f);

    for (int c0 = 0; c0 < deg; c0 += 64) {
        const int cl = min(64, deg - c0);
        if (l < cl) {
            int s = csr[base + c0 + l];
            float4 a = als4[s];
            float4 sc = lrelu4(make_float4(a.x + adv.x, a.y + adv.y,
                                           a.z + adv.z, a.w + adv.w));
            float4 ex = make_float4(__expf(sc.x), __expf(sc.y),
                                    __expf(sc.z), __expf(sc.w));
            *(float4*)&s_alpha[w][l][0] = ex;
            s_src[w][l] = s;
            esum.x += ex.x; esum.y += ex.y; esum.z += ex.z; esum.w += ex.w;
        }
        int e = 0;
        for (; e + 8 <= cl; e += 8) {
            int si[8]; float ai[8]; float4 vi[8];
#pragma unroll
            for (int t = 0; t < 8; ++t) {
                si[t] = s_src[w][e + t];
                ai[t] = s_alpha[w][e + t][head];
            }
#pragma unroll
            for (int t = 0; t < 8; ++t)
                vi[t] = *(const float4*)(h + (size_t)si[t] * 256 + l * 4);
#pragma unroll
            for (int t = 0; t < 8; ++t) {
                acc.x = fmaf(ai[t], vi[t].x, acc.x);
                acc.y = fmaf(ai[t], vi[t].y, acc.y);
                acc.z = fmaf(ai[t], vi[t].z, acc.z);
                acc.w = fmaf(ai[t], vi[t].w, acc.w);
            }
        }
        for (; e + 4 <= cl; e += 4) {
            int si[4]; float ai[4]; float4 vi[4];
#pragma unroll
            for (int t = 0; t < 4; ++t) {
                si[t] = s_src[w][e + t];
                ai[t] = s_alpha[w][e + t][head];
            }
#pragma unroll
            for (int t = 0; t < 4; ++t)
                vi[t] = *(const float4*)(h + (size_t)si[t] * 256 + l * 4);
#pragma unroll
            for (int t = 0; t < 4; ++t) {
                acc.x = fmaf(ai[t], vi[t].x, acc.x);
                acc.y = fmaf(ai[t], vi[t].y, acc.y);
                acc.z = fmaf(ai[t], vi[t].z, acc.z);
                acc.w = fmaf(ai[t], vi[t].w, acc.w);
            }
        }
        for (; e < cl; ++e) {
            int s0 = s_src[w][e];
            float a0 = s_alpha[w][e][head];
            float4 v0 = *(const float4*)(h + (size_t)s0 * 256 + l * 4);
            acc.x = fmaf(a0, v0.x, acc.x); acc.y = fmaf(a0, v0.y, acc.y);
            acc.z = fmaf(a0, v0.z, acc.z); acc.w = fmaf(a0, v0.w, acc.w);
        }
    }
    esum.x = wave_allred_sum(esum.x); esum.y = wave_allred_sum(esum.y);
    esum.z = wave_allred_sum(esum.z); esum.w = wave_allred_sum(esum.w);
    float d = (head == 0) ? esum.x : (head == 1) ? esum.y
             : (head == 2) ? esum.z : esum.w;
    const float rc = 1.f / (d + EPS_SM);

    float4 bv = *(const float4*)(bias + l * 4);
    float4 r = make_float4(acc.x * rc + bv.x, acc.y * rc + bv.y,
                           acc.z * rc + bv.z, acc.w * rc + bv.w);
    r.x = (r.x > 0.f) ? r.x : expm1f(r.x);
    r.y = (r.y > 0.f) ? r.y : expm1f(r.y);
    r.z = (r.z > 0.f) ? r.z : expm1f(r.z);
    r.w = (r.w > 0.f) ? r.w : expm1f(r.w);
    unsigned u0 = __float_as_uint(r.x), u1 = __float_as_uint(r.y);
    unsigned u2 = __float_as_uint(r.z), u3 = __float_as_uint(r.w);
    unsigned h01 = (u0 >> 16) | (u1 & 0xffff0000u);
    unsigned h23 = (u2 >> 16) | (u3 & 0xffff0000u);
    float d0 = r.x - __uint_as_float(u0 & 0xffff0000u);
    float d1 = r.y - __uint_as_float(u1 & 0xffff0000u);
    float d2 = r.z - __uint_as_float(u2 & 0xffff0000u);
    float d3 = r.w - __uint_as_float(u3 & 0xffff0000u);
    unsigned l01 = (__float_as_uint(d0) >> 16) | (__float_as_uint(d1) & 0xffff0000u);
    unsigned l23 = (__float_as_uint(d2) >> 16) | (__float_as_uint(d3) & 0xffff0000u);
    *(uint2*)(yh + (size_t)n * 256 + l * 4) = make_uint2(h01, h23);
    *(uint2*)(yl + (size_t)n * 256 + l * 4) = make_uint2(l01, l23);
}

// ---------------- single-pass aggregation H=1 C=128 ----------------
__global__ __launch_bounds__(256) void aggregate_h1_sp(
    const float* __restrict__ h, const float* __restrict__ als,
    const float* __restrict__ ald, const int* __restrict__ offs,
    const int* __restrict__ csr, const float* __restrict__ bias,
    float* __restrict__ out, int Nn) {
    const int tid = threadIdx.x;
    const int w = tid >> 6;
    const int l = tid & 63;
    const int n = blockIdx.x * 4 + w;
    __shared__ float s_alpha[4][64];
    __shared__ int s_src[4][64];
    if (n >= Nn) return;

    const int base = offs[n];
    const int deg = offs[n + 1] - base;
    const float ad_n = ald[n];

    float2 acc = make_float2(0.f, 0.f);
    float esum = 0.f;

    for (int c0 = 0; c0 < deg; c0 += 64) {
        const int cl = min(64, deg - c0);
        if (l < cl) {
            int s = csr[base + c0 + l];
            float sc = als[s] + ad_n;
            sc = (sc < 0.f) ? NEG_SLOPE * sc : sc;
            float ex = __expf(sc);
            s_alpha[w][l] = ex;
            s_src[w][l] = s;
            esum += ex;
        }
        int e = 0;
        for (; e + 8 <= cl; e += 8) {
            int si[8]; float ai[8]; float2 vi[8];
#pragma unroll
            for (int t = 0; t < 8; ++t) {
                si[t] = s_src[w][e + t];
                ai[t] = s_alpha[w][e + t];
            }
#pragma unroll
            for (int t = 0; t < 8; ++t)
                vi[t] = *(const float2*)(h + (size_t)si[t] * 128 + l * 2);
#pragma unroll
            for (int t = 0; t < 8; ++t) {
                acc.x = fmaf(ai[t], vi[t].x, acc.x);
                acc.y = fmaf(ai[t], vi[t].y, acc.y);
            }
        }
        for (; e < cl; ++e) {
            int s0 = s_src[w][e];
            float a0 = s_alpha[w][e];
            float2 v0 = *(const float2*)(h + (size_t)s0 * 128 + l * 2);
            acc.x = fmaf(a0, v0.x, acc.x); acc.y = fmaf(a0, v0.y, acc.y);
        }
    }
    esum = wave_allred_sum(esum);
    const float rc = 1.f / (esum + EPS_SM);
    float2 r = make_float2(acc.x * rc + bias[l * 2],
                           acc.y * rc + bias[l * 2 + 1]);
    *(float2*)(out + (size_t)n * 128 + l * 2) = r;
}

// ---------------------------------------------------------------------------
extern "C" void kernel_launch(void* const* d_in, const int* in_sizes, int n_in,
                              void* d_out, int out_size, void* d_ws,
                              size_t ws_size, hipStream_t stream) {
    const float* x   = (const float*)d_in[0];
    const int*   ei  = (const int*)d_in[1];
    const float* W1  = (const float*)d_in[2];
    const float* as1 = (const float*)d_in[3];
    const float* ad1 = (const float*)d_in[4];
    const float* b1  = (const float*)d_in[5];
    const float* W2  = (const float*)d_in[6];
    const float* as2 = (const float*)d_in[7];
    const float* ad2 = (const float*)d_in[8];
    const float* b2  = (const float*)d_in[9];
    const float* W3  = (const float*)d_in[10];
    const float* as3 = (const float*)d_in[11];
    const float* ad3 = (const float*)d_in[12];
    const float* b3  = (const float*)d_in[13];

    const int Nn = in_sizes[0] / 256;   // 50000 nodes
    const int E  = in_sizes[1] / 2;     // 800000 edges
    const int ET = E + Nn;

    // workspace carve
    char* p = (char*)d_ws;
    float* bufA = (float*)p; p += (size_t)Nn * 256 * 4;            // h (f32)
    unsigned short* ahi = (unsigned short*)p; p += (size_t)Nn * 256 * 2;
    unsigned short* alo = (unsigned short*)p; p += (size_t)Nn * 256 * 2;
    float* als  = (float*)p; p += (size_t)Nn * 4 * 4;
    float* ald  = (float*)p; p += (size_t)Nn * 4 * 4;
    int* cnt  = (int*)p; p += (size_t)Nn * 4;
    int* fil  = (int*)p; p += (size_t)Nn * 4;
    int* offs = (int*)p; p += (size_t)(Nn + 1) * 4;
    int* bsums = (int*)p; p += 256 * 4;
    int* csr  = (int*)p; p += (size_t)ET * 4;
    p = (char*)(((uintptr_t)p + 15) & ~(uintptr_t)15);
    unsigned short* wt1h = (unsigned short*)p; p += 256 * 256 * 2;
    unsigned short* wt1l = (unsigned short*)p; p += 256 * 256 * 2;
    unsigned short* wt2h = (unsigned short*)p; p += 256 * 256 * 2;
    unsigned short* wt2l = (unsigned short*)p; p += 256 * 256 * 2;
    unsigned short* wt3h = (unsigned short*)p; p += 128 * 256 * 2;
    unsigned short* wt3l = (unsigned short*)p; p += 128 * 256 * 2;

    // --- CSR build + weight splits + x split ---
    hipMemsetAsync(cnt, 0, (size_t)2 * Nn * sizeof(int), stream);
    int nbE = (ET + 255) / 256;
    hist_kernel<<<nbE, 256, 0, stream>>>(ei, E, Nn, cnt);
    wsplit_t<<<(256 * 256 + 255) / 256, 256, 0, stream>>>(W1, 256, 256, wt1h, wt1l);
    wsplit_t<<<(256 * 256 + 255) / 256, 256, 0, stream>>>(W2, 256, 256, wt2h, wt2l);
    wsplit_t<<<(128 * 256 + 255) / 256, 256, 0, stream>>>(W3, 256, 128, wt3h, wt3l);
    {
        int total8 = Nn * 256 / 8;
        split_x<<<(total8 + 255) / 256, 256, 0, stream>>>(x, ahi, alo, total8);
    }
    int nbS = (Nn + 1 + 1023) / 1024;
    scan_block<<<nbS, 1024, 0, stream>>>(cnt, Nn, offs, Nn + 1, bsums);
    scan_sums<<<1, 64, 0, stream>>>(bsums, nbS);
    scan_add<<<nbS, 1024, 0, stream>>>(offs, Nn + 1, bsums);
    fill_csr<<<nbE, 256, 0, stream>>>(ei, E, Nn, offs, fil, csr);

    const int gm = (Nn + 127) / 128;   // 391
    const int ga = (Nn + 3) / 4;       // 12500

    // --- layer 1: 256 -> 256, H=4, C=64, ELU ---
    gemm_mfma_wide<<<gm, 512, 0, stream>>>(
        ahi, alo, wt1h, wt1l, bufA, as1, ad1, als, ald, Nn);
    aggregate_h4_sp<<<ga, 256, 0, stream>>>(
        bufA, (const float4*)als, (const float4*)ald, offs, csr, b1, ahi, alo, Nn);

    // --- layer 2: 256 -> 256, H=4, C=64, ELU ---
    gemm_mfma_wide<<<gm, 512, 0, stream>>>(
        ahi, alo, wt2h, wt2l, bufA, as2, ad2, als, ald, Nn);
    aggregate_h4_sp<<<ga, 256, 0, stream>>>(
        bufA, (const float4*)als, (const float4*)ald, offs, csr, b2, ahi, alo, Nn);

    // --- layer 3: 256 -> 128, H=1, C=128, no act ---
    hipMemsetAsync(als, 0, (size_t)2 * Nn * 4 * sizeof(float), stream);  // als+ald
    gemm_mfma_n128<<<gm, 256, 0, stream>>>(
        ahi, alo, wt3h, wt3l, bufA, as3, ad3, als, ald, Nn);
    aggregate_h1_sp<<<ga, 256, 0, stream>>>(
        bufA, als, ald, offs, csr, b3, (float*)d_out, Nn);
}

// Round 9
// 648.472 us; speedup vs baseline: 1.0143x; 1.0143x over previous
//
#include <hip/hip_runtime.h>
#include <hip/hip_bf16.h>
#include <math.h>

// ---------------------------------------------------------------------------
// GAT 3-layer forward.
// R9: (a) GEMM BM 128->64 (grid 782 ~ 3.05 blocks/CU: fixes the 1.53/CU
//         imbalance), (b) prep kernels (hist + wsplit x3 + split_x) fused
//         into one launch, (c) agg_h1 gathers with half-wave float4 rows.
//     Aggregates are at the memory-stream roofline (logical ~6.6 TB/s).
// ---------------------------------------------------------------------------

#define NEG_SLOPE 0.2f
#define EPS_SM 1e-16f

typedef __bf16 bf16x8 __attribute__((ext_vector_type(8)));
typedef float f32x4 __attribute__((ext_vector_type(4)));

__device__ __forceinline__ void async_copy16(unsigned short* ldsdst,
                                             const unsigned short* g) {
    __builtin_amdgcn_global_load_lds(
        (const __attribute__((address_space(1))) unsigned int*)g,
        (__attribute__((address_space(3))) unsigned int*)ldsdst, 16, 0, 0);
}

__device__ __forceinline__ float wave_allred_sum(float v) {
#pragma unroll
    for (int o = 32; o > 0; o >>= 1) v += __shfl_xor(v, o, 64);
    return v;
}
__device__ __forceinline__ float4 lrelu4(float4 v) {
    v.x = (v.x < 0.f) ? NEG_SLOPE * v.x : v.x;
    v.y = (v.y < 0.f) ? NEG_SLOPE * v.y : v.y;
    v.z = (v.z < 0.f) ? NEG_SLOPE * v.z : v.z;
    v.w = (v.w < 0.f) ? NEG_SLOPE * v.w : v.w;
    return v;
}

// ---------------- fused prep: hist + W-splits + X-split ----------------
__device__ __forceinline__ void wsplit_body(const float* W, int K, int N,
                                            unsigned short* hi,
                                            unsigned short* lo, int idx) {
    if (idx >= N * K) return;
    int n = idx / K, k = idx - n * K;
    float v = W[(size_t)k * N + n];
    unsigned u = __float_as_uint(v);
    float d = v - __uint_as_float(u & 0xffff0000u);
    hi[idx] = (unsigned short)(u >> 16);
    lo[idx] = (unsigned short)(__float_as_uint(d) >> 16);
}

__global__ void prep_all(const int* __restrict__ ei, int E, int N,
                         int* __restrict__ cnt,
                         const float* __restrict__ W1, unsigned short* wt1h,
                         unsigned short* wt1l,
                         const float* __restrict__ W2, unsigned short* wt2h,
                         unsigned short* wt2l,
                         const float* __restrict__ W3, unsigned short* wt3h,
                         unsigned short* wt3l,
                         const float* __restrict__ X, unsigned short* ahi,
                         unsigned short* alo, int nbE, int total8) {
    const int b = blockIdx.x;
    const int tid = threadIdx.x;
    if (b < nbE) {
        int e = b * 256 + tid;
        int ET = E + N;
        if (e >= ET) return;
        int dst = (e < E) ? ei[E + e] : (e - E);
        atomicAdd(&cnt[dst], 1);
    } else if (b < nbE + 256) {
        wsplit_body(W1, 256, 256, wt1h, wt1l, (b - nbE) * 256 + tid);
    } else if (b < nbE + 512) {
        wsplit_body(W2, 256, 256, wt2h, wt2l, (b - nbE - 256) * 256 + tid);
    } else if (b < nbE + 640) {
        wsplit_body(W3, 256, 128, wt3h, wt3l, (b - nbE - 512) * 256 + tid);
    } else {
        int idx = (b - nbE - 640) * 256 + tid;
        if (idx >= total8) return;
        const float4* xp = (const float4*)X + (size_t)idx * 2;
        float4 v0 = xp[0], v1 = xp[1];
        float vf[8] = {v0.x, v0.y, v0.z, v0.w, v1.x, v1.y, v1.z, v1.w};
        unsigned h[4], l[4];
#pragma unroll
        for (int i = 0; i < 4; ++i) {
            unsigned u0 = __float_as_uint(vf[2 * i]);
            unsigned u1 = __float_as_uint(vf[2 * i + 1]);
            h[i] = (u0 >> 16) | (u1 & 0xffff0000u);
            float d0 = vf[2 * i]     - __uint_as_float(u0 & 0xffff0000u);
            float d1 = vf[2 * i + 1] - __uint_as_float(u1 & 0xffff0000u);
            l[i] = (__float_as_uint(d0) >> 16) |
                   (__float_as_uint(d1) & 0xffff0000u);
        }
        ((uint4*)ahi)[idx] = make_uint4(h[0], h[1], h[2], h[3]);
        ((uint4*)alo)[idx] = make_uint4(l[0], l[1], l[2], l[3]);
    }
}

// ---------------- CSR scan / fill ----------------
__global__ void scan_block(const int* __restrict__ cnt, int n_cnt,
                           int* __restrict__ offs, int n_off,
                           int* __restrict__ bsums) {
    __shared__ int buf[1024];
    int gid = blockIdx.x * 1024 + threadIdx.x;
    int v = (gid < n_cnt) ? cnt[gid] : 0;
    buf[threadIdx.x] = v;
    __syncthreads();
#pragma unroll
    for (int off = 1; off < 1024; off <<= 1) {
        int t = (threadIdx.x >= off) ? buf[threadIdx.x - off] : 0;
        __syncthreads();
        buf[threadIdx.x] += t;
        __syncthreads();
    }
    if (gid < n_off) offs[gid] = buf[threadIdx.x] - v;
    if (threadIdx.x == 1023) bsums[blockIdx.x] = buf[1023];
}

__global__ void scan_sums(int* __restrict__ bsums, int nb) {
    int l = threadIdx.x;
    int v = (l < nb) ? bsums[l] : 0;
    int inc = v;
#pragma unroll
    for (int o = 1; o < 64; o <<= 1) {
        int t = __shfl_up(inc, o, 64);
        if (l >= o) inc += t;
    }
    if (l < nb) bsums[l] = inc - v;  // exclusive
}

__global__ void scan_add(int* __restrict__ offs, int n_off,
                         const int* __restrict__ bsums) {
    int gid = blockIdx.x * 1024 + threadIdx.x;
    if (gid < n_off) offs[gid] += bsums[blockIdx.x];
}

__global__ void fill_csr(const int* __restrict__ ei, int E, int N,
                         const int* __restrict__ offs, int* __restrict__ fil,
                         int* __restrict__ csr) {
    int e = blockIdx.x * 256 + threadIdx.x;
    int ET = E + N;
    if (e >= ET) return;
    int src, dst;
    if (e < E) { src = ei[e]; dst = ei[E + e]; }
    else       { src = dst = e - E; }
    int pos = offs[dst] + atomicAdd(&fil[dst], 1);
    csr[pos] = src;
}

// ---------------- layers 1-2 GEMM: BM=64 BN=256 BK=32, 256 thr -------------
// async staging, XOR swizzle; 4 waves, wave w -> cols w*64..w*64+63.
// LDS ushorts: Ah[0,2048) Al[2048,4096) Bh[4096,12288) Bl[12288,20480)
__global__ __launch_bounds__(256) void gemm_mfma_wide(
    const unsigned short* __restrict__ A_hi,
    const unsigned short* __restrict__ A_lo,
    const unsigned short* __restrict__ Bt_hi,
    const unsigned short* __restrict__ Bt_lo, float* __restrict__ C,
    const float* __restrict__ a_s, const float* __restrict__ a_d,
    float* __restrict__ als, float* __restrict__ ald, int M) {
    const int K = 256, N = 256;
    __shared__ unsigned short lds[20480];  // 40 KB
    const int bm = blockIdx.x * 64;
    const int tid = threadIdx.x;
    const int w = tid >> 6, lane = tid & 63;
    const int wn = w * 64;
    const int l16 = lane & 15, q = lane >> 4;
    const int sw = (l16 >> 1) & 3;
    const int kqp = (q ^ sw) * 8;
    const int rl = lane >> 2, kc = lane & 3;

    f32x4 acc[4][4];
#pragma unroll
    for (int i = 0; i < 4; ++i)
#pragma unroll
        for (int j = 0; j < 4; ++j) acc[i][j] = (f32x4){0.f, 0.f, 0.f, 0.f};

    for (int k0 = 0; k0 < K; k0 += 32) {
        // 40 x 1KB chunks; wave w does chunks w*10..w*10+9
#pragma unroll
        for (int j = 0; j < 10; ++j) {
            const int c = w * 10 + j;
            const unsigned short* src;
            int row0, ldsbase, isA;
            if (c < 4)       { src = A_hi;  row0 = c * 16;        ldsbase = c * 512;             isA = 1; }
            else if (c < 8)  { src = A_lo;  row0 = (c - 4) * 16;  ldsbase = 2048 + (c-4)*512;    isA = 1; }
            else if (c < 24) { src = Bt_hi; row0 = (c - 8) * 16;  ldsbase = 4096 + (c-8)*512;    isA = 0; }
            else             { src = Bt_lo; row0 = (c - 24) * 16; ldsbase = 12288 + (c-24)*512;  isA = 0; }
            const int r = row0 + rl;
            const int gcol = k0 + ((kc ^ ((r >> 1) & 3)) * 8);
            if (isA) {
                if (bm + r < M)
                    async_copy16(&lds[ldsbase], src + (size_t)(bm + r) * K + gcol);
            } else {
                async_copy16(&lds[ldsbase], src + (size_t)r * K + gcol);
            }
        }
        __syncthreads();
        bf16x8 aH[4], aL[4], bH[4], bL[4];
#pragma unroll
        for (int t = 0; t < 4; ++t) {
            aH[t] = *(const bf16x8*)&lds[(t * 16 + l16) * 32 + kqp];
            aL[t] = *(const bf16x8*)&lds[2048 + (t * 16 + l16) * 32 + kqp];
            bH[t] = *(const bf16x8*)&lds[4096 + (wn + t * 16 + l16) * 32 + kqp];
            bL[t] = *(const bf16x8*)&lds[12288 + (wn + t * 16 + l16) * 32 + kqp];
        }
#pragma unroll
        for (int i = 0; i < 4; ++i)
#pragma unroll
            for (int j = 0; j < 4; ++j) {
                acc[i][j] = __builtin_amdgcn_mfma_f32_16x16x32_bf16(
                    aH[i], bH[j], acc[i][j], 0, 0, 0);
                acc[i][j] = __builtin_amdgcn_mfma_f32_16x16x32_bf16(
                    aH[i], bL[j], acc[i][j], 0, 0, 0);
                acc[i][j] = __builtin_amdgcn_mfma_f32_16x16x32_bf16(
                    aL[i], bH[j], acc[i][j], 0, 0, 0);
            }
        __syncthreads();
    }

    // epilogue 1: C store (C/D layout: col = l16, row = q*4 + reg)
#pragma unroll
    for (int i = 0; i < 4; ++i) {
#pragma unroll
        for (int r = 0; r < 4; ++r) {
            int row = bm + i * 16 + q * 4 + r;
            if (row < M) {
                float* cp = C + (size_t)row * N + wn + l16;
                cp[0]  = acc[i][0][r];
                cp[16] = acc[i][1][r];
                cp[32] = acc[i][2][r];
                cp[48] = acc[i][3][r];
            }
        }
    }

    // epilogue 2: fused al_s / al_d (wave w owns head w)
    const int head = w;
    float asc[4], adc[4];
#pragma unroll
    for (int j = 0; j < 4; ++j) {
        asc[j] = a_s[head * 64 + 16 * j + l16];
        adc[j] = a_d[head * 64 + 16 * j + l16];
    }
#pragma unroll
    for (int i = 0; i < 4; ++i) {
#pragma unroll
        for (int r = 0; r < 4; ++r) {
            float ps = acc[i][0][r] * asc[0] + acc[i][1][r] * asc[1] +
                       acc[i][2][r] * asc[2] + acc[i][3][r] * asc[3];
            float pd = acc[i][0][r] * adc[0] + acc[i][1][r] * adc[1] +
                       acc[i][2][r] * adc[2] + acc[i][3][r] * adc[3];
#pragma unroll
            for (int o = 1; o < 16; o <<= 1) {
                ps += __shfl_xor(ps, o, 64);
                pd += __shfl_xor(pd, o, 64);
            }
            int row = bm + i * 16 + q * 4 + r;
            if (l16 == i * 4 + r && row < M) {
                als[row * 4 + head] = ps;
                ald[row * 4 + head] = pd;
            }
        }
    }
}

// ---------------- layer-3 GEMM: BM=64 BN=128 BK=32, 128 thr ----------------
// LDS ushorts: Ah[0,2048) Al[2048,4096) Bh[4096,8192) Bl[8192,12288)
__global__ __launch_bounds__(128) void gemm_mfma_n128(
    const unsigned short* __restrict__ A_hi,
    const unsigned short* __restrict__ A_lo,
    const unsigned short* __restrict__ Bt_hi,
    const unsigned short* __restrict__ Bt_lo, float* __restrict__ C,
    const float* __restrict__ a_s, const float* __restrict__ a_d,
    float* __restrict__ als, float* __restrict__ ald, int M) {
    const int K = 256, N = 128;
    __shared__ unsigned short lds[12288];  // 24 KB
    const int bm = blockIdx.x * 64;
    const int tid = threadIdx.x;
    const int w = tid >> 6, lane = tid & 63;
    const int wn = w * 64;
    const int l16 = lane & 15, q = lane >> 4;
    const int sw = (l16 >> 1) & 3;
    const int kqp = (q ^ sw) * 8;
    const int rl = lane >> 2, kc = lane & 3;

    f32x4 acc[4][4];
#pragma unroll
    for (int i = 0; i < 4; ++i)
#pragma unroll
        for (int j = 0; j < 4; ++j) acc[i][j] = (f32x4){0.f, 0.f, 0.f, 0.f};

    for (int k0 = 0; k0 < K; k0 += 32) {
        // 24 x 1KB chunks; wave w does chunks w*12..w*12+11
#pragma unroll
        for (int j = 0; j < 12; ++j) {
            const int c = w * 12 + j;
            const unsigned short* src;
            int row0, ldsbase, isA;
            if (c < 4)       { src = A_hi;  row0 = c * 16;        ldsbase = c * 512;            isA = 1; }
            else if (c < 8)  { src = A_lo;  row0 = (c - 4) * 16;  ldsbase = 2048 + (c-4)*512;   isA = 1; }
            else if (c < 16) { src = Bt_hi; row0 = (c - 8) * 16;  ldsbase = 4096 + (c-8)*512;   isA = 0; }
            else             { src = Bt_lo; row0 = (c - 16) * 16; ldsbase = 8192 + (c-16)*512;  isA = 0; }
            const int r = row0 + rl;
            const int gcol = k0 + ((kc ^ ((r >> 1) & 3)) * 8);
            if (isA) {
                if (bm + r < M)
                    async_copy16(&lds[ldsbase], src + (size_t)(bm + r) * K + gcol);
            } else {
                async_copy16(&lds[ldsbase], src + (size_t)r * K + gcol);
            }
        }
        __syncthreads();
        bf16x8 aH[4], aL[4], bH[4], bL[4];
#pragma unroll
        for (int t = 0; t < 4; ++t) {
            aH[t] = *(const bf16x8*)&lds[(t * 16 + l16) * 32 + kqp];
            aL[t] = *(const bf16x8*)&lds[2048 + (t * 16 + l16) * 32 + kqp];
            bH[t] = *(const bf16x8*)&lds[4096 + (wn + t * 16 + l16) * 32 + kqp];
            bL[t] = *(const bf16x8*)&lds[8192 + (wn + t * 16 + l16) * 32 + kqp];
        }
#pragma unroll
        for (int i = 0; i < 4; ++i)
#pragma unroll
            for (int j = 0; j < 4; ++j) {
                acc[i][j] = __builtin_amdgcn_mfma_f32_16x16x32_bf16(
                    aH[i], bH[j], acc[i][j], 0, 0, 0);
                acc[i][j] = __builtin_amdgcn_mfma_f32_16x16x32_bf16(
                    aH[i], bL[j], acc[i][j], 0, 0, 0);
                acc[i][j] = __builtin_amdgcn_mfma_f32_16x16x32_bf16(
                    aL[i], bH[j], acc[i][j], 0, 0, 0);
            }
        __syncthreads();
    }

#pragma unroll
    for (int i = 0; i < 4; ++i) {
#pragma unroll
        for (int r = 0; r < 4; ++r) {
            int row = bm + i * 16 + q * 4 + r;
            if (row < M) {
                float* cp = C + (size_t)row * N + wn + l16;
                cp[0]  = acc[i][0][r];
                cp[16] = acc[i][1][r];
                cp[32] = acc[i][2][r];
                cp[48] = acc[i][3][r];
            }
        }
    }

    float asc[4], adc[4];
#pragma unroll
    for (int j = 0; j < 4; ++j) {
        asc[j] = a_s[wn + 16 * j + l16];
        adc[j] = a_d[wn + 16 * j + l16];
    }
#pragma unroll
    for (int i = 0; i < 4; ++i) {
#pragma unroll
        for (int r = 0; r < 4; ++r) {
            float ps = acc[i][0][r] * asc[0] + acc[i][1][r] * asc[1] +
                       acc[i][2][r] * asc[2] + acc[i][3][r] * asc[3];
            float pd = acc[i][0][r] * adc[0] + acc[i][1][r] * adc[1] +
                       acc[i][2][r] * adc[2] + acc[i][3][r] * adc[3];
#pragma unroll
            for (int o = 1; o < 16; o <<= 1) {
                ps += __shfl_xor(ps, o, 64);
                pd += __shfl_xor(pd, o, 64);
            }
            int row = bm + i * 16 + q * 4 + r;
            if (l16 == i * 4 + r && row < M) {
                atomicAdd(&als[row], ps);
                atomicAdd(&ald[row], pd);
            }
        }
    }
}

// ---------------- single-pass aggregation H=4 C=64 ----------------
__global__ __launch_bounds__(256) void aggregate_h4_sp(
    const float* __restrict__ h, const float4* __restrict__ als4,
    const float4* __restrict__ ald4, const int* __restrict__ offs,
    const int* __restrict__ csr, const float* __restrict__ bias,
    unsigned short* __restrict__ yh, unsigned short* __restrict__ yl, int Nn) {
    const int tid = threadIdx.x;
    const int w = tid >> 6;
    const int l = tid & 63;
    const int n = blockIdx.x * 4 + w;
    __shared__ float s_alpha[4][64][4];
    __shared__ int s_src[4][64];
    if (n >= Nn) return;

    const int base = offs[n];
    const int deg = offs[n + 1] - base;
    const float4 adv = ald4[n];
    const int head = l >> 4;

    float4 acc = make_float4(0.f, 0.f, 0.f, 0.f);
    float4 esum = make_float4(0.f, 0.f, 0.f, 0.f);

    for (int c0 = 0; c0 < deg; c0 += 64) {
        const int cl = min(64, deg - c0);
        if (l < cl) {
            int s = csr[base + c0 + l];
            float4 a = als4[s];
            float4 sc = lrelu4(make_float4(a.x + adv.x, a.y + adv.y,
                                           a.z + adv.z, a.w + adv.w));
            float4 ex = make_float4(__expf(sc.x), __expf(sc.y),
                                    __expf(sc.z), __expf(sc.w));
            *(float4*)&s_alpha[w][l][0] = ex;
            s_src[w][l] = s;
            esum.x += ex.x; esum.y += ex.y; esum.z += ex.z; esum.w += ex.w;
        }
        int e = 0;
        for (; e + 8 <= cl; e += 8) {
            int si[8]; float ai[8]; float4 vi[8];
#pragma unroll
            for (int t = 0; t < 8; ++t) {
                si[t] = s_src[w][e + t];
                ai[t] = s_alpha[w][e + t][head];
            }
#pragma unroll
            for (int t = 0; t < 8; ++t)
                vi[t] = *(const float4*)(h + (size_t)si[t] * 256 + l * 4);
#pragma unroll
            for (int t = 0; t < 8; ++t) {
                acc.x = fmaf(ai[t], vi[t].x, acc.x);
                acc.y = fmaf(ai[t], vi[t].y, acc.y);
                acc.z = fmaf(ai[t], vi[t].z, acc.z);
                acc.w = fmaf(ai[t], vi[t].w, acc.w);
            }
        }
        for (; e + 4 <= cl; e += 4) {
            int si[4]; float ai[4]; float4 vi[4];
#pragma unroll
            for (int t = 0; t < 4; ++t) {
                si[t] = s_src[w][e + t];
                ai[t] = s_alpha[w][e + t][head];
            }
#pragma unroll
            for (int t = 0; t < 4; ++t)
                vi[t] = *(const float4*)(h + (size_t)si[t] * 256 + l * 4);
#pragma unroll
            for (int t = 0; t < 4; ++t) {
                acc.x = fmaf(ai[t], vi[t].x, acc.x);
                acc.y = fmaf(ai[t], vi[t].y, acc.y);
                acc.z = fmaf(ai[t], vi[t].z, acc.z);
                acc.w = fmaf(ai[t], vi[t].w, acc.w);
            }
        }
        for (; e < cl; ++e) {
            int s0 = s_src[w][e];
            float a0 = s_alpha[w][e][head];
            float4 v0 = *(const float4*)(h + (size_t)s0 * 256 + l * 4);
            acc.x = fmaf(a0, v0.x, acc.x); acc.y = fmaf(a0, v0.y, acc.y);
            acc.z = fmaf(a0, v0.z, acc.z); acc.w = fmaf(a0, v0.w, acc.w);
        }
    }
    esum.x = wave_allred_sum(esum.x); esum.y = wave_allred_sum(esum.y);
    esum.z = wave_allred_sum(esum.z); esum.w = wave_allred_sum(esum.w);
    float d = (head == 0) ? esum.x : (head == 1) ? esum.y
             : (head == 2) ? esum.z : esum.w;
    const float rc = 1.f / (d + EPS_SM);

    float4 bv = *(const float4*)(bias + l * 4);
    float4 r = make_float4(acc.x * rc + bv.x, acc.y * rc + bv.y,
                           acc.z * rc + bv.z, acc.w * rc + bv.w);
    r.x = (r.x > 0.f) ? r.x : expm1f(r.x);
    r.y = (r.y > 0.f) ? r.y : expm1f(r.y);
    r.z = (r.z > 0.f) ? r.z : expm1f(r.z);
    r.w = (r.w > 0.f) ? r.w : expm1f(r.w);
    unsigned u0 = __float_as_uint(r.x), u1 = __float_as_uint(r.y);
    unsigned u2 = __float_as_uint(r.z), u3 = __float_as_uint(r.w);
    unsigned h01 = (u0 >> 16) | (u1 & 0xffff0000u);
    unsigned h23 = (u2 >> 16) | (u3 & 0xffff0000u);
    float d0 = r.x - __uint_as_float(u0 & 0xffff0000u);
    float d1 = r.y - __uint_as_float(u1 & 0xffff0000u);
    float d2 = r.z - __uint_as_float(u2 & 0xffff0000u);
    float d3 = r.w - __uint_as_float(u3 & 0xffff0000u);
    unsigned l01 = (__float_as_uint(d0) >> 16) | (__float_as_uint(d1) & 0xffff0000u);
    unsigned l23 = (__float_as_uint(d2) >> 16) | (__float_as_uint(d3) & 0xffff0000u);
    *(uint2*)(yh + (size_t)n * 256 + l * 4) = make_uint2(h01, h23);
    *(uint2*)(yl + (size_t)n * 256 + l * 4) = make_uint2(l01, l23);
}

// ---------------- single-pass aggregation H=1 C=128, half-wave rows --------
__global__ __launch_bounds__(256) void aggregate_h1_sp(
    const float* __restrict__ h, const float* __restrict__ als,
    const float* __restrict__ ald, const int* __restrict__ offs,
    const int* __restrict__ csr, const float* __restrict__ bias,
    float* __restrict__ out, int Nn) {
    const int tid = threadIdx.x;
    const int w = tid >> 6;
    const int l = tid & 63;
    const int hw = l >> 5;          // half-wave id
    const int c4 = (l & 31) * 4;    // this lane's 4 channels
    const int n = blockIdx.x * 4 + w;
    __shared__ float s_alpha[4][64];
    __shared__ int s_src[4][64];
    if (n >= Nn) return;

    const int base = offs[n];
    const int deg = offs[n + 1] - base;
    const float ad_n = ald[n];

    float4 acc = make_float4(0.f, 0.f, 0.f, 0.f);
    float esum = 0.f;

    for (int c0 = 0; c0 < deg; c0 += 64) {
        const int cl = min(64, deg - c0);
        if (l < cl) {
            int s = csr[base + c0 + l];
            float sc = als[s] + ad_n;
            sc = (sc < 0.f) ? NEG_SLOPE * sc : sc;
            float ex = __expf(sc);
            s_alpha[w][l] = ex;
            s_src[w][l] = s;
            esum += ex;
        }
        // each half-wave gathers one full 512B row per step (2 edges/wave)
        int e = 0;
        for (; e + 16 <= cl; e += 16) {
            int si[8]; float ai[8]; float4 vi[8];
#pragma unroll
            for (int t = 0; t < 8; ++t) {
                int ee = e + 2 * t + hw;
                si[t] = s_src[w][ee];
                ai[t] = s_alpha[w][ee];
            }
#pragma unroll
            for (int t = 0; t < 8; ++t)
                vi[t] = *(const float4*)(h + (size_t)si[t] * 128 + c4);
#pragma unroll
            for (int t = 0; t < 8; ++t) {
                acc.x = fmaf(ai[t], vi[t].x, acc.x);
                acc.y = fmaf(ai[t], vi[t].y, acc.y);
                acc.z = fmaf(ai[t], vi[t].z, acc.z);
                acc.w = fmaf(ai[t], vi[t].w, acc.w);
            }
        }
        for (; e < cl; e += 2) {
            int ee = e + hw;
            if (ee < cl) {
                int s0 = s_src[w][ee];
                float a0 = s_alpha[w][ee];
                float4 v0 = *(const float4*)(h + (size_t)s0 * 128 + c4);
                acc.x = fmaf(a0, v0.x, acc.x);
                acc.y = fmaf(a0, v0.y, acc.y);
                acc.z = fmaf(a0, v0.z, acc.z);
                acc.w = fmaf(a0, v0.w, acc.w);
            }
        }
    }
    esum = wave_allred_sum(esum);
    const float rc = 1.f / (esum + EPS_SM);
    // combine halves (lane l and l+32 hold the same channels)
    acc.x += __shfl_xor(acc.x, 32, 64);
    acc.y += __shfl_xor(acc.y, 32, 64);
    acc.z += __shfl_xor(acc.z, 32, 64);
    acc.w += __shfl_xor(acc.w, 32, 64);
    if (hw == 0) {
        float4 bv = *(const float4*)(bias + c4);
        float4 r = make_float4(acc.x * rc + bv.x, acc.y * rc + bv.y,
                               acc.z * rc + bv.z, acc.w * rc + bv.w);
        *(float4*)(out + (size_t)n * 128 + c4) = r;
    }
}

// ---------------------------------------------------------------------------
extern "C" void kernel_launch(void* const* d_in, const int* in_sizes, int n_in,
                              void* d_out, int out_size, void* d_ws,
                              size_t ws_size, hipStream_t stream) {
    const float* x   = (const float*)d_in[0];
    const int*   ei  = (const int*)d_in[1];
    const float* W1  = (const float*)d_in[2];
    const float* as1 = (const float*)d_in[3];
    const float* ad1 = (const float*)d_in[4];
    const float* b1  = (const float*)d_in[5];
    const float* W2  = (const float*)d_in[6];
    const float* as2 = (const float*)d_in[7];
    const float* ad2 = (const float*)d_in[8];
    const float* b2  = (const float*)d_in[9];
    const float* W3  = (const float*)d_in[10];
    const float* as3 = (const float*)d_in[11];
    const float* ad3 = (const float*)d_in[12];
    const float* b3  = (const float*)d_in[13];

    const int Nn = in_sizes[0] / 256;   // 50000 nodes
    const int E  = in_sizes[1] / 2;     // 800000 edges
    const int ET = E + Nn;

    // workspace carve
    char* p = (char*)d_ws;
    float* bufA = (float*)p; p += (size_t)Nn * 256 * 4;            // h (f32)
    unsigned short* ahi = (unsigned short*)p; p += (size_t)Nn * 256 * 2;
    unsigned short* alo = (unsigned short*)p; p += (size_t)Nn * 256 * 2;
    float* als  = (float*)p; p += (size_t)Nn * 4 * 4;
    float* ald  = (float*)p; p += (size_t)Nn * 4 * 4;
    int* cnt  = (int*)p; p += (size_t)Nn * 4;
    int* fil  = (int*)p; p += (size_t)Nn * 4;
    int* offs = (int*)p; p += (size_t)(Nn + 1) * 4;
    int* bsums = (int*)p; p += 256 * 4;
    int* csr  = (int*)p; p += (size_t)ET * 4;
    p = (char*)(((uintptr_t)p + 15) & ~(uintptr_t)15);
    unsigned short* wt1h = (unsigned short*)p; p += 256 * 256 * 2;
    unsigned short* wt1l = (unsigned short*)p; p += 256 * 256 * 2;
    unsigned short* wt2h = (unsigned short*)p; p += 256 * 256 * 2;
    unsigned short* wt2l = (unsigned short*)p; p += 256 * 256 * 2;
    unsigned short* wt3h = (unsigned short*)p; p += 128 * 256 * 2;
    unsigned short* wt3l = (unsigned short*)p; p += 128 * 256 * 2;

    // --- fused prep + CSR build ---
    hipMemsetAsync(cnt, 0, (size_t)2 * Nn * sizeof(int), stream);
    int nbE = (ET + 255) / 256;
    int total8 = Nn * 256 / 8;
    int nbX = (total8 + 255) / 256;
    prep_all<<<nbE + 640 + nbX, 256, 0, stream>>>(
        ei, E, Nn, cnt, W1, wt1h, wt1l, W2, wt2h, wt2l, W3, wt3h, wt3l,
        x, ahi, alo, nbE, total8);
    int nbS = (Nn + 1 + 1023) / 1024;
    scan_block<<<nbS, 1024, 0, stream>>>(cnt, Nn, offs, Nn + 1, bsums);
    scan_sums<<<1, 64, 0, stream>>>(bsums, nbS);
    scan_add<<<nbS, 1024, 0, stream>>>(offs, Nn + 1, bsums);
    fill_csr<<<nbE, 256, 0, stream>>>(ei, E, Nn, offs, fil, csr);

    const int gm = (Nn + 63) / 64;     // 782
    const int ga = (Nn + 3) / 4;       // 12500

    // --- layer 1: 256 -> 256, H=4, C=64, ELU ---
    gemm_mfma_wide<<<gm, 256, 0, stream>>>(
        ahi, alo, wt1h, wt1l, bufA, as1, ad1, als, ald, Nn);
    aggregate_h4_sp<<<ga, 256, 0, stream>>>(
        bufA, (const float4*)als, (const float4*)ald, offs, csr, b1, ahi, alo, Nn);

    // --- layer 2: 256 -> 256, H=4, C=64, ELU ---
    gemm_mfma_wide<<<gm, 256, 0, stream>>>(
        ahi, alo, wt2h, wt2l, bufA, as2, ad2, als, ald, Nn);
    aggregate_h4_sp<<<ga, 256, 0, stream>>>(
        bufA, (const float4*)als, (const float4*)ald, offs, csr, b2, ahi, alo, Nn);

    // --- layer 3: 256 -> 128, H=1, C=128, no act ---
    hipMemsetAsync(als, 0, (size_t)2 * Nn * 4 * sizeof(float), stream);  // als+ald
    gemm_mfma_n128<<<gm, 128, 0, stream>>>(
        ahi, alo, wt3h, wt3l, bufA, as3, ad3, als, ald, Nn);
    aggregate_h1_sp<<<ga, 256, 0, stream>>>(
        bufA, als, ald, offs, csr, b3, (float*)d_out, Nn);
}